// Round 2
// baseline (1794.557 us; speedup 1.0000x reference)
//
#include <hip/hip_runtime.h>
#include <math.h>

#define T_ENC 2048
#define BATCH 32
#define DM    256
#define HID   512
#define VOC   32
#define LEN   100

// ws layout (floats):
// [0,      65536)   enc_score -> (after softmax, in place) aw   [b][t]
// [65536, 196608)   ctx_part [tg][b][d]   (16*32*256)
// [196608,204800)   ctx [b][d]
// [204800,253952)   gi_const [b][1536]    (ctx-part of gi + b_ih)
// [253952,303104)   gi_emb   [v][1536]    (emb-part of gi)
// [303104,319488)   hT buf0  [k][b]       (transposed h, 512x32)
// [319488,335872)   hT buf1
// total ~1.31 MB

// ---------- precompute ----------

// enc_score[b][t] = sum_d enc[t][b][d] * W_attn[512+d]   (one wave per (b,t))
__global__ void k_score(const float* __restrict__ enc, const float* __restrict__ Wattn,
                        float* __restrict__ score) {
  int wid  = (blockIdx.x * blockDim.x + threadIdx.x) >> 6;
  int lane = threadIdx.x & 63;
  int b = wid & 31, t = wid >> 5;
  const float4 e4 = *(const float4*)(enc + (size_t)(t * BATCH + b) * DM + lane * 4);
  const float4 w4 = *(const float4*)(Wattn + HID + lane * 4);
  float v = e4.x * w4.x + e4.y * w4.y + e4.z * w4.z + e4.w * w4.w;
  for (int o = 32; o; o >>= 1) v += __shfl_down(v, o);
  if (lane == 0) score[b * T_ENC + t] = v;
}

// softmax over t, in place. 32 blocks x 256 threads (8 elems/thread).
__global__ void k_softmax(float* __restrict__ score) {
  int b = blockIdx.x, tid = threadIdx.x;
  float* row = score + b * T_ENC;
  float4 v0 = *(const float4*)(row + tid * 8);
  float4 v1 = *(const float4*)(row + tid * 8 + 4);
  float m = fmaxf(fmaxf(fmaxf(v0.x, v0.y), fmaxf(v0.z, v0.w)),
                  fmaxf(fmaxf(v1.x, v1.y), fmaxf(v1.z, v1.w)));
  for (int o = 32; o; o >>= 1) m = fmaxf(m, __shfl_xor(m, o));
  __shared__ float redm[8];
  __shared__ float reds[8];
  if ((tid & 63) == 0) redm[tid >> 6] = m;
  __syncthreads();
  m = fmaxf(fmaxf(redm[0], redm[1]), fmaxf(redm[2], redm[3]));
  float e0 = expf(v0.x - m), e1 = expf(v0.y - m), e2 = expf(v0.z - m), e3 = expf(v0.w - m);
  float e4 = expf(v1.x - m), e5 = expf(v1.y - m), e6 = expf(v1.z - m), e7 = expf(v1.w - m);
  float s = ((e0 + e1) + (e2 + e3)) + ((e4 + e5) + (e6 + e7));
  for (int o = 32; o; o >>= 1) s += __shfl_xor(s, o);
  if ((tid & 63) == 0) reds[tid >> 6] = s;
  __syncthreads();
  s = (reds[0] + reds[1]) + (reds[2] + reds[3]);
  float inv = 1.f / s;
  float4 o0 = {e0 * inv, e1 * inv, e2 * inv, e3 * inv};
  float4 o1 = {e4 * inv, e5 * inv, e6 * inv, e7 * inv};
  *(float4*)(row + tid * 8)     = o0;
  *(float4*)(row + tid * 8 + 4) = o1;
}

// ctx partial sums over t-groups of 128. grid (b*16+tg) = 512 blocks x 256 thr.
__global__ void k_ctxpart(const float* __restrict__ enc, const float* __restrict__ aw,
                          float* __restrict__ ctx_part) {
  int b = blockIdx.x >> 4, tg = blockIdx.x & 15;
  int w = threadIdx.x >> 6, lane = threadIdx.x & 63;
  float4 acc = {0.f, 0.f, 0.f, 0.f};
  for (int i = 0; i < 32; ++i) {
    int t = tg * 128 + w * 32 + i;
    float a = aw[b * T_ENC + t];
    const float4 e4 = *(const float4*)(enc + (size_t)(t * BATCH + b) * DM + lane * 4);
    acc.x += a * e4.x; acc.y += a * e4.y; acc.z += a * e4.z; acc.w += a * e4.w;
  }
  __shared__ float4 part[4][64];
  part[w][lane] = acc;
  __syncthreads();
  if (w == 0) {
    float4 s = part[0][lane], p1 = part[1][lane], p2 = part[2][lane], p3 = part[3][lane];
    s.x += p1.x + p2.x + p3.x; s.y += p1.y + p2.y + p3.y;
    s.z += p1.z + p2.z + p3.z; s.w += p1.w + p2.w + p3.w;
    *(float4*)(ctx_part + (size_t)(tg * BATCH + b) * DM + lane * 4) = s;
  }
}

// reduce 16 partials -> ctx[b][d]. 32 blocks x 256 thr.
__global__ void k_ctxreduce(const float* __restrict__ ctx_part, float* __restrict__ ctx) {
  int b = blockIdx.x, d = threadIdx.x;
  float s = 0.f;
  for (int tg = 0; tg < 16; ++tg) s += ctx_part[(size_t)(tg * BATCH + b) * DM + d];
  ctx[b * DM + d] = s;
}

// gi tables: gi_const[b][row] = ctx[b] . W_ih[row, 256:512] + b_ih[row]
//            gi_emb[v][row]   = emb[v] . W_ih[row, 0:256]
// 192 blocks x 256 thr; tid = (rowslot<<5)|idx
__global__ void k_gitab(const float* __restrict__ Wih, const float* __restrict__ bih,
                        const float* __restrict__ emb, const float* __restrict__ ctx,
                        float* __restrict__ gi_const, float* __restrict__ gi_emb) {
  int idx = threadIdx.x & 31, rs = threadIdx.x >> 5;
  int row = blockIdx.x * 8 + rs;
  const float* wr = Wih + (size_t)row * (2 * DM);
  const float* c = ctx + idx * DM;
  const float* e = emb + idx * DM;
  float accC = 0.f, accE = 0.f;
  for (int k = 0; k < DM; k += 4) {
    float4 we = *(const float4*)(wr + k);
    float4 wc = *(const float4*)(wr + DM + k);
    float4 cv = *(const float4*)(c + k);
    float4 ev = *(const float4*)(e + k);
    accE += we.x * ev.x + we.y * ev.y + we.z * ev.z + we.w * ev.w;
    accC += wc.x * cv.x + wc.y * cv.y + wc.z * cv.z + wc.w * cv.w;
  }
  gi_const[idx * 1536 + row] = accC + bih[row];
  gi_emb[idx * 1536 + row]   = accE;
}

// init: zero h0, out[b][i][v] = b_out[v] (atomic pred accumulates on top)
__global__ void k_init(float* __restrict__ h0, float* __restrict__ out,
                       const float* __restrict__ b_out) {
  int i = blockIdx.x * blockDim.x + threadIdx.x;
  if (i < HID * BATCH) h0[i] = 0.f;
  for (int j = i; j < BATCH * LEN * VOC; j += gridDim.x * blockDim.x)
    out[j] = b_out[j & 31];
}

// ---------- recurrent step ----------
// 128 blocks x 768 threads. Block bk owns h-dims [bk*4, bk*4+4).
// thread: b = tid&31, grp = tid>>5 in [0,24): ks = grp>=12 (k-half),
//         slot = grp-12*ks in [0,12): dd = slot&3, gate g = slot>>2.
__global__ __launch_bounds__(768) void k_step(
    const float* __restrict__ Whh, const float* __restrict__ bhh,
    const float* __restrict__ Wout,
    const float* __restrict__ gi_const, const float* __restrict__ gi_emb,
    const float* __restrict__ hA, float* __restrict__ hB,
    float* __restrict__ out, int step) {
  __shared__ int   tokLds[BATCH];
  __shared__ float gh_part[2][12][BATCH];
  __shared__ float hnew_lds[4][BATCH];
  int tid = threadIdx.x;
  int bk  = blockIdx.x;

  // phase 0: tok = argmax(pred_{step-1}) (redundant per block; reads d_out)
  if (tid < BATCH) {
    int tok = 1;  // SOS
    if (step > 0) {
      const float* p = out + (size_t)(tid * LEN + (step - 1)) * VOC;
      float best = p[0]; tok = 0;
      for (int v = 1; v < VOC; ++v) { float x = p[v]; if (x > best) { best = x; tok = v; } }
    }
    tokLds[tid] = tok;
  }

  // phase 1: gh_part[ks][slot][b] = W_hh[row, ks*256:(ks+1)*256] . h[ks-half, b]
  int b = tid & 31, grp = tid >> 5;
  int ks = (grp >= 12) ? 1 : 0;
  int slot = grp - 12 * ks;
  int dd = slot & 3, g = slot >> 2;
  int row = g * HID + bk * 4 + dd;
  const float* wr = Whh + (size_t)row * HID + ks * 256;
  const float* hk = hA + ks * 256 * BATCH;
  float a0 = 0.f, a1 = 0.f, a2 = 0.f, a3 = 0.f;
#pragma unroll 4
  for (int k = 0; k < 256; k += 4) {
    float4 w4 = *(const float4*)(wr + k);
    a0 += w4.x * hk[(k    ) * BATCH + b];
    a1 += w4.y * hk[(k + 1) * BATCH + b];
    a2 += w4.z * hk[(k + 2) * BATCH + b];
    a3 += w4.w * hk[(k + 3) * BATCH + b];
  }
  float part = (a0 + a1) + (a2 + a3);
  if (ks == 0) part += bhh[row];
  gh_part[ks][slot][b] = part;
  __syncthreads();

  // phase 2: gates + h_new (tid < 128: slot in [0,4) == dd, g == 0)
  if (tid < 128) {
    int d = bk * 4 + (tid >> 5);
    int slot2 = tid >> 5;
    int tok = tokLds[b];
    const float* ge = gi_emb + (size_t)tok * 1536;
    const float* gc = gi_const + (size_t)b * 1536;
    float gir = ge[d]        + gc[d];
    float giz = ge[512 + d]  + gc[512 + d];
    float gin = ge[1024 + d] + gc[1024 + d];
    float ghr = gh_part[0][slot2][b]     + gh_part[1][slot2][b];
    float ghz = gh_part[0][4 + slot2][b] + gh_part[1][4 + slot2][b];
    float ghn = gh_part[0][8 + slot2][b] + gh_part[1][8 + slot2][b];
    float r = 1.f / (1.f + expf(-(gir + ghr)));
    float z = 1.f / (1.f + expf(-(giz + ghz)));
    float n = tanhf(gin + r * ghn);
    float h_old = hA[d * BATCH + b];
    float hn = (1.f - z) * n + z * h_old;
    hB[d * BATCH + b] = hn;
    hnew_lds[slot2][b] = hn;
  }
  __syncthreads();

  // phase 3: partial pred into out (pre-initialized to b_out)
  for (int idx = tid; idx < BATCH * VOC; idx += 768) {
    int pb = idx >> 5, v = idx & 31;
    const float* wo = Wout + (size_t)v * HID + bk * 4;
    float c = hnew_lds[0][pb] * wo[0] + hnew_lds[1][pb] * wo[1] +
              hnew_lds[2][pb] * wo[2] + hnew_lds[3][pb] * wo[3];
    atomicAdd(out + (size_t)(pb * LEN + step) * VOC + v, c);
  }
}

extern "C" void kernel_launch(void* const* d_in, const int* in_sizes, int n_in,
                              void* d_out, int out_size, void* d_ws, size_t ws_size,
                              hipStream_t stream) {
  (void)in_sizes; (void)n_in; (void)out_size; (void)ws_size;
  const float* enc   = (const float*)d_in[0];
  const float* emb   = (const float*)d_in[1];
  const float* Wattn = (const float*)d_in[2];
  // d_in[3] b_attn: constant shift, cancels in softmax
  const float* Wih  = (const float*)d_in[4];
  const float* Whh  = (const float*)d_in[5];
  const float* bih  = (const float*)d_in[6];
  const float* bhh  = (const float*)d_in[7];
  const float* Wout = (const float*)d_in[8];
  const float* bout = (const float*)d_in[9];

  float* ws       = (float*)d_ws;
  float* score    = ws;               // 65536
  float* ctx_part = ws + 65536;       // 131072
  float* ctx      = ws + 196608;      // 8192
  float* gic      = ws + 204800;      // 49152
  float* gie      = ws + 253952;      // 49152
  float* h0       = ws + 303104;      // 16384
  float* h1       = ws + 319488;      // 16384
  float* out      = (float*)d_out;

  k_init<<<64, 256, 0, stream>>>(h0, out, bout);
  k_score<<<16384, 256, 0, stream>>>(enc, Wattn, score);
  k_softmax<<<32, 256, 0, stream>>>(score);
  k_ctxpart<<<512, 256, 0, stream>>>(enc, score, ctx_part);
  k_ctxreduce<<<32, 256, 0, stream>>>(ctx_part, ctx);
  k_gitab<<<192, 256, 0, stream>>>(Wih, bih, emb, ctx, gic, gie);

  for (int i = 0; i < LEN; ++i) {
    const float* ha = (i & 1) ? h1 : h0;
    float*       hb = (i & 1) ? h0 : h1;
    k_step<<<128, 768, 0, stream>>>(Whh, bhh, Wout, gic, gie, ha, hb, out, i);
  }
}